// Round 11
// baseline (188.996 us; speedup 1.0000x reference)
//
#include <hip/hip_runtime.h>
#include <hip/hip_bf16.h>

typedef __attribute__((ext_vector_type(8))) short bf16x8;
typedef __attribute__((ext_vector_type(4))) float f32x4;
typedef __attribute__((ext_vector_type(16))) float f32x16;
typedef __attribute__((ext_vector_type(4))) int i32x4;

#define DEVI __device__ __forceinline__

namespace {
constexpr int BATCH = 2;
constexpr int T = 4096;
constexpr int C = 768;
constexpr int H = 12;
constexpr int HD = 64;
constexpr int M = BATCH * T;     // 8192
constexpr int N3 = 3 * C;        // 2304
constexpr int BH = BATCH * H;    // 24
constexpr float QSCALE = 0.125f * 1.44269504088896f;  // 1/sqrt(64) * log2(e)
constexpr int PSZ = 64 * 128 + 128;  // partial: O^T f32 [64d][128q] + l[128]
}  // namespace

DEVI ushort f2b(float f) {
  union { float f; unsigned u; } v; v.f = f;
  unsigned r = (v.u + 0x7FFFu + ((v.u >> 16) & 1u)) >> 16;
  return (ushort)r;
}

DEVI f32x16 zero16() {
  f32x16 z;
#pragma unroll
  for (int i = 0; i < 16; i++) z[i] = 0.f;
  return z;
}

// async 16B global->LDS. LDS dest is wave-uniform base; HW adds lane*16.
DEVI void gload16(const void* g, void* l) {
  __builtin_amdgcn_global_load_lds(
      (const __attribute__((address_space(1))) unsigned int*)g,
      (__attribute__((address_space(3))) unsigned int*)l, 16, 0, 0);
}

__global__ __launch_bounds__(256) void cvt_kernel(const float* __restrict__ src,
                                                  ushort* __restrict__ dst, int n) {
  int i = (blockIdx.x * 256 + threadIdx.x) * 4;
  int stride = gridDim.x * 256 * 4;
  for (; i < n; i += stride) {
    float4 v = *reinterpret_cast<const float4*>(src + i);
    ushort4 o;
    o.x = f2b(v.x); o.y = f2b(v.y); o.z = f2b(v.z); o.w = f2b(v.w);
    *reinterpret_cast<ushort4*>(dst + i) = o;
  }
}

// Transpose-convert: f32 W [K][N] -> bf16 W^T [N][K]. 64x64 tiles.
__global__ __launch_bounds__(256) void cvtT_kernel(const float* __restrict__ src,
                                                   ushort* __restrict__ dst,
                                                   int K, int N) {
  __shared__ ushort Lt[64 * 68];
  const int k0 = blockIdx.x * 64, n0 = blockIdx.y * 64;
  const int tid = threadIdx.x;
  const int rr = tid >> 4, c4 = (tid & 15) * 4;
#pragma unroll
  for (int it = 0; it < 4; it++) {
    const int r = it * 16 + rr;
    float4 v = *reinterpret_cast<const float4*>(src + (size_t)(k0 + r) * N + n0 + c4);
    Lt[(c4 + 0) * 68 + r] = f2b(v.x);
    Lt[(c4 + 1) * 68 + r] = f2b(v.y);
    Lt[(c4 + 2) * 68 + r] = f2b(v.z);
    Lt[(c4 + 3) * 68 + r] = f2b(v.w);
  }
  __syncthreads();
#pragma unroll
  for (int it = 0; it < 4; it++) {
    const int r = it * 16 + rr;
    *reinterpret_cast<ushort4*>(dst + (size_t)(n0 + r) * K + k0 + c4) =
        *reinterpret_cast<const ushort4*>(&Lt[r * 68 + c4]);
  }
}

// m97-style GEMM: A [Mrows x Kd] bf16 row-major, Bt = B^T [N x Kd] bf16 row-major.
template <int EPI>
__global__ __launch_bounds__(256, 3) void gemm_kernel(
    const ushort* __restrict__ A, const ushort* __restrict__ Bt,
    const float* __restrict__ bias, int N, int Kd,
    ushort* __restrict__ qo, ushort* __restrict__ ko, ushort* __restrict__ vo,
    float* __restrict__ fo) {
  constexpr int BM = 128;
  constexpr int BN = 128;
  constexpr int WN = 2;                    // waves along n
  constexpr int WTN = BN / WN;             // 64
  constexpr int NT = WTN / 32;             // 2
  constexpr int CH_A = BM / 8;             // 1KB chunks in A tile
  constexpr int CH_B = BN / 8;
  constexpr int CPW = (CH_A + CH_B) / 4;
  constexpr int SMEM = (EPI == 0) ? (4 * 64 * 68) : ((BM + BN) * 64);
  __shared__ ushort smem[SMEM];
  ushort* As = smem;
  ushort* Bs = smem + BM * 64;

  const int tid = threadIdx.x;
  const int lane = tid & 63;
  const int w = tid >> 6;
  const int l31 = lane & 31;
  const int hi = lane >> 5;
  const int wm = w / WN, wn = w % WN;
  const int m0 = blockIdx.y * BM, n0 = blockIdx.x * BN;
  const int r8 = lane >> 3, c8 = lane & 7;
  const int csw = (c8 ^ r8) * 8;

  f32x16 acc[2][NT];
#pragma unroll
  for (int mt = 0; mt < 2; mt++)
#pragma unroll
    for (int nt = 0; nt < NT; nt++) acc[mt][nt] = zero16();

  for (int k0 = 0; k0 < Kd; k0 += 64) {
    __syncthreads();
#pragma unroll
    for (int ci = 0; ci < CPW; ci++) {
      const int chk = w * CPW + ci;
      if (chk < CH_A) {
        gload16(A + (size_t)(m0 + chk * 8 + r8) * Kd + k0 + csw, (char*)As + chk * 1024);
      } else {
        const int ch2 = chk - CH_A;
        gload16(Bt + (size_t)(n0 + ch2 * 8 + r8) * Kd + k0 + csw, (char*)Bs + ch2 * 1024);
      }
    }
    __syncthreads();
#pragma unroll
    for (int ks = 0; ks < 4; ks++) {
      bf16x8 af[2], bf[NT];
#pragma unroll
      for (int mt = 0; mt < 2; mt++) {
        const int rl = wm * 64 + mt * 32 + l31;
        af[mt] = *reinterpret_cast<const bf16x8*>(
            &As[rl * 64 + ((ks * 16 + hi * 8) ^ ((rl & 7) * 8))]);
      }
#pragma unroll
      for (int nt = 0; nt < NT; nt++) {
        const int nl = wn * WTN + nt * 32 + l31;
        bf[nt] = *reinterpret_cast<const bf16x8*>(
            &Bs[nl * 64 + ((ks * 16 + hi * 8) ^ ((nl & 7) * 8))]);
      }
#pragma unroll
      for (int mt = 0; mt < 2; mt++)
#pragma unroll
        for (int nt = 0; nt < NT; nt++)
          acc[mt][nt] = __builtin_amdgcn_mfma_f32_32x32x16_bf16(af[mt], bf[nt], acc[mt][nt], 0, 0, 0);
    }
  }

  // C layout (verified): col = l31, row = (r&3) + 8*(r>>2) + 4*hi
  if constexpr (EPI == 0) {
    if (n0 >= 1536) {
      __syncthreads();
      ushort* Vw = smem + w * 4352;  // [64 d][68]
      const float bv0 = bias[n0 + wn * 64 + l31];
      const float bv1 = bias[n0 + wn * 64 + 32 + l31];
#pragma unroll
      for (int mt = 0; mt < 2; mt++)
#pragma unroll
        for (int nt = 0; nt < 2; nt++) {
          const float bv = nt ? bv1 : bv0;
#pragma unroll
          for (int r = 0; r < 16; r++) {
            const int trow = mt * 32 + (r & 3) + ((r >> 2) << 3) + (hi << 2);
            Vw[(nt * 32 + l31) * 68 + trow] = f2b(acc[mt][nt][r] + bv);
          }
        }
      const int hh = (n0 - 1536) / 64 + wn;
      const int bb = m0 >> 12;
      const int t0 = (m0 & (T - 1)) + wm * 64;
      const size_t vbase = (size_t)((bb * H + hh) * 64 + lane) * T + t0;
#pragma unroll
      for (int x8 = 0; x8 < 8; x8++) {
        bf16x8 vv = *reinterpret_cast<const bf16x8*>(&Vw[lane * 68 + x8 * 8]);
        *reinterpret_cast<bf16x8*>(vo + vbase + ((x8 ^ (lane & 7)) * 8)) = vv;
      }
    } else {
#pragma unroll
      for (int mt = 0; mt < 2; mt++)
#pragma unroll
        for (int nt = 0; nt < 2; nt++) {
          const int n = n0 + wn * 64 + nt * 32 + l31;
          const float bv = bias[n];
          const int part = (n >= 768) ? 1 : 0;
          const int ci = n - part * 768;
          const int hh = ci >> 6, dd = ci & 63;
#pragma unroll
          for (int r = 0; r < 16; r++) {
            const int m = m0 + wm * 64 + mt * 32 + (r & 3) + ((r >> 2) << 3) + (hi << 2);
            const int bb = m >> 12, t = m & (T - 1);
            const float val = acc[mt][nt][r] + bv;
            if (part == 0) {
              qo[((size_t)(bb * H + hh) * T + t) * HD + dd] = f2b(val * QSCALE);
            } else {
              ko[((size_t)(bb * H + hh) * T + t) * HD + (dd ^ ((t & 7) << 3))] = f2b(val);
            }
          }
        }
    }
  } else {
#pragma unroll
    for (int mt = 0; mt < 2; mt++)
#pragma unroll
      for (int nt = 0; nt < NT; nt++) {
        const int n = n0 + wn * WTN + nt * 32 + l31;
        const float bv = bias[n];
#pragma unroll
        for (int r = 0; r < 16; r++) {
          const int m = m0 + wm * 64 + mt * 32 + (r & 3) + ((r >> 2) << 3) + (hi << 2);
          fo[(size_t)m * N + n] = acc[mt][nt][r] + bv;
        }
      }
  }
}

// Flash attention v11: 4 waves x 32q = 128q tile, KVBLK=128, zero-shift softmax
// (p = exp2(s) directly), row-sums via ones-MFMA, persistent zero C-operand.
// K single-buf + V double-buf, 2 barriers/tile. 768 uniform blocks (16-17 tiles).
__global__ __launch_bounds__(256, 3) void attn_kernel(
    const ushort* __restrict__ Qg, const ushort* __restrict__ Kg,
    const ushort* __restrict__ Vtg, ushort* __restrict__ Yg,
    float* __restrict__ Pp) {
  __shared__ ushort kbuf[128 * 64];         // 16KB: K [128kv][64k^swz]
  __shared__ ushort vbuf[2 * 2 * 64 * 64];  // 32KB: parity x kv64-subtile x [64d][64kv^swz]

  const int tid = threadIdx.x;
  const int lane = tid & 63;
  const int w = tid >> 6;            // 0..3
  const int l31 = lane & 31;
  const int hi = lane >> 5;
  const int r8 = lane >> 3, c8 = lane & 7;

  const int bid = blockIdx.x;
  const int xcd = bid & 7, idx = bid >> 3;   // 8 XCDs x 96
  const int bh = xcd * 3 + idx % 3;          // 3 heads per XCD (L2 locality)
  const int slot = idx / 3;                  // 0..31

  int qtA, qtB, kvbase, bnd, ntot, pA, pB;
  if (slot < 8) {
    qtA = slot; qtB = 15 - slot; kvbase = 0; bnd = slot + 1; ntot = 17; pA = -1; pB = -1;
  } else if (slot < 24) {
    qtA = slot + 8; qtB = -1; kvbase = 0; bnd = 100; ntot = 16;
    pA = (bh * 16 + (qtA - 16)) * 2; pB = -1;
  } else {
    const int a = slot - 24;
    qtA = 16 + a; qtB = 31 - a; kvbase = 16; bnd = a + 1; ntot = 17;
    pA = (bh * 16 + a) * 2 + 1; pB = (bh * 16 + (15 - a)) * 2 + 1;
  }

  const int bb = bh / H, h = bh % H;
  const ushort* Qp = Qg + (size_t)bh * T * HD;
  const char* Kbp = (const char*)(Kg + (size_t)bh * T * HD);
  const char* Vbp = (const char*)(Vtg + (size_t)bh * HD * T);

  bf16x8 qcur[4];
#pragma unroll
  for (int ks = 0; ks < 4; ks++)
    qcur[ks] = *reinterpret_cast<const bf16x8*>(
        Qp + (size_t)(qtA * 128 + w * 32 + l31) * HD + ks * 16 + hi * 8);

  int q0 = qtA * 128, q0w = q0 + w * 32, qc = q0w + l31;
  int pcur = pA;

  const f32x16 ZF = zero16();  // persistent zero C-operand (never modified)
  const i32x4 onesi = {0x3F803F80, 0x3F803F80, 0x3F803F80, 0x3F803F80};
  const bf16x8 onesf = __builtin_bit_cast(bf16x8, onesi);  // bf16 1.0 x8

  f32x16 o16[2];
  o16[0] = zero16();
  o16[1] = zero16();
  f32x16 o_l = zero16();  // every reg = running row-sum l (via ones-MFMA)
  const int swz = (l31 & 7) << 3;

  auto issue_K = [&](int kvt) {
    const int kv0 = kvt * 128;
#pragma unroll
    for (int c2 = 0; c2 < 4; c2++) {
      const int chk = w * 4 + c2;  // 0..15, 8 kv-rows each
      gload16(Kbp + ((size_t)(kv0 + chk * 8 + r8) * 64 + c8 * 8) * 2,
              (char*)kbuf + chk * 1024);
    }
  };
  auto issue_V = [&](int kvt, int par) {
    const int kv0 = kvt * 128;
#pragma unroll
    for (int c2 = 0; c2 < 4; c2++) {
      const int chk = w * 4 + c2;       // 0..15
      const int st = chk >> 3;          // kv 64-block
      const int d8 = chk & 7;           // d-row group
      gload16(Vbp + ((size_t)(d8 * 8 + r8) * T + kv0 + st * 64 + c8 * 8) * 2,
              (char*)vbuf + par * 16384 + chk * 1024);
    }
  };

  auto epilogue = [&](int q0p, float lr, ushort* Ytb) {
    ushort* Yw = Ytb + w * 1152;  // per-wave [32 q][36]
    const float linv = 1.0f / lr;
#pragma unroll
    for (int dt = 0; dt < 2; dt++) {
#pragma unroll
      for (int r = 0; r < 16; r++) {
        const int d32 = (r & 3) + ((r >> 2) << 3) + (hi << 2);
        Yw[l31 * 36 + d32] = f2b(o16[dt][r] * linv);
      }
#pragma unroll
      for (int seg = 0; seg < 2; seg++) {
        bf16x8 vv = *reinterpret_cast<const bf16x8*>(&Yw[l31 * 36 + hi * 16 + seg * 8]);
        *reinterpret_cast<bf16x8*>(
            Yg + ((size_t)(bb * T + q0p + w * 32 + l31)) * C + h * 64 + dt * 32 +
            hi * 16 + seg * 8) = vv;
      }
    }
  };

  auto pwrite = [&](float* P, float lr) {
#pragma unroll
    for (int dt = 0; dt < 2; dt++)
#pragma unroll
      for (int r = 0; r < 16; r++) {
        const int d = dt * 32 + (r & 3) + ((r >> 2) << 3) + (hi << 2);
        P[d * 128 + w * 32 + l31] = o16[dt][r];
      }
    P[8192 + w * 32 + l31] = lr;
  };

  issue_K(kvbase);
  issue_V(kvbase, 0);

  for (int tt = 0; tt < ntot; tt++) {
    asm volatile("s_waitcnt vmcnt(0)" ::: "memory");  // K(tt) and V(tt) landed
    __builtin_amdgcn_s_barrier();
    __builtin_amdgcn_sched_barrier(0);

    if (tt == bnd) {  // flush pass A, switch to pass B
      const float lr = o_l[0];
      if (pcur >= 0) pwrite(Pp + (size_t)pcur * PSZ, lr);
      else epilogue(q0, lr, vbuf + ((tt + 1) & 1) * 8192);  // dead V half
      o16[0] = zero16(); o16[1] = zero16(); o_l = zero16();
#pragma unroll
      for (int ks = 0; ks < 4; ks++)
        qcur[ks] = *reinterpret_cast<const bf16x8*>(
            Qp + (size_t)(qtB * 128 + w * 32 + l31) * HD + ks * 16 + hi * 8);
      q0 = qtB * 128; q0w = q0 + w * 32; qc = q0w + l31; pcur = pB;
    }

    const int kvt = kvbase + (tt < bnd ? tt : tt - bnd);
    const int kv0 = kvt * 128;
    bool have[4], needm[4];
#pragma unroll
    for (int sub = 0; sub < 4; sub++) {
      have[sub] = (kv0 + sub * 32) <= (q0w + 31);
      needm[sub] = (kv0 + sub * 32 + 31) > q0w;  // false on full tiles
    }

    // S^T = K x Q^T, 4 kv-subs (first MFMA consumes persistent ZF; no re-zeroing)
    f32x16 s2[4];
#pragma unroll
    for (int sub = 0; sub < 4; sub++) {
      if (!have[sub]) continue;
      const int row = sub * 32 + l31;
      __builtin_amdgcn_s_setprio(1);
      bf16x8 kf = *reinterpret_cast<const bf16x8*>(&kbuf[row * 64 + ((hi * 8) ^ swz)]);
      f32x16 acc = __builtin_amdgcn_mfma_f32_32x32x16_bf16(kf, qcur[0], ZF, 0, 0, 0);
#pragma unroll
      for (int ks = 1; ks < 4; ks++) {
        kf = *reinterpret_cast<const bf16x8*>(
            &kbuf[row * 64 + ((ks * 16 + hi * 8) ^ swz)]);
        acc = __builtin_amdgcn_mfma_f32_32x32x16_bf16(kf, qcur[ks], acc, 0, 0, 0);
      }
      __builtin_amdgcn_s_setprio(0);
      if (needm[sub]) {
#pragma unroll
        for (int r2 = 0; r2 < 16; r2++) {
          const int kv = kv0 + sub * 32 + (r2 & 3) + ((r2 >> 2) << 3) + (hi << 2);
          if (kv > qc) acc[r2] = -1e30f;
        }
      }
      s2[sub] = acc;
    }

    asm volatile("s_waitcnt lgkmcnt(0)" ::: "memory");  // kbuf consumed
    __builtin_amdgcn_s_barrier();
    __builtin_amdgcn_sched_barrier(0);
    if (tt + 1 < ntot) {  // prefetch flies under softmax + PV
      const int nkvt = kvbase + ((tt + 1) < bnd ? (tt + 1) : (tt + 1) - bnd);
      issue_K(nkvt);
      issue_V(nkvt, (tt + 1) & 1);
    }

    // zero-shift softmax: p = exp2(s). Masked entries exp2(-1e30) -> 0.
#pragma unroll
    for (int sub = 0; sub < 4; sub++) {
      if (!have[sub]) continue;
#pragma unroll
      for (int r2 = 0; r2 < 16; r2++)
        s2[sub][r2] = __builtin_amdgcn_exp2f(s2[sub][r2]);
    }

    // PV from vbuf[tt&1]; l accumulated via ones-MFMA (row-sum over kv)
    const ushort* Vpar = vbuf + (tt & 1) * 8192;
#pragma unroll
    for (int sub = 0; sub < 4; sub++) {
      if (!have[sub]) continue;
      const ushort* Vst = Vpar + (sub >> 1) * 4096;
      const int colb = (sub & 1) * 32;
#pragma unroll
      for (int ks2 = 0; ks2 < 2; ks2++) {
        const int r0 = ks2 * 8;
        int a0, a1, b0, b1;
        asm("v_cvt_pk_bf16_f32 %0, %1, %2" : "=v"(a0) : "v"(s2[sub][r0 + 0]), "v"(s2[sub][r0 + 1]));
        asm("v_cvt_pk_bf16_f32 %0, %1, %2" : "=v"(a1) : "v"(s2[sub][r0 + 2]), "v"(s2[sub][r0 + 3]));
        asm("v_cvt_pk_bf16_f32 %0, %1, %2" : "=v"(b0) : "v"(s2[sub][r0 + 4]), "v"(s2[sub][r0 + 5]));
        asm("v_cvt_pk_bf16_f32 %0, %1, %2" : "=v"(b1) : "v"(s2[sub][r0 + 6]), "v"(s2[sub][r0 + 7]));
        asm("v_permlane32_swap_b32 %0, %1" : "+v"(a0), "+v"(b0));
        asm("v_permlane32_swap_b32 %0, %1" : "+v"(a1), "+v"(b1));
        const i32x4 pi = {a0, a1, b0, b1};
        const bf16x8 pf = __builtin_bit_cast(bf16x8, pi);
        __builtin_amdgcn_s_setprio(1);
#pragma unroll
        for (int dt = 0; dt < 2; dt++) {
          const int drow = dt * 32 + l31;
          const int sw2 = (drow & 7) << 3;
          bf16x8 vf = *reinterpret_cast<const bf16x8*>(
              &Vst[drow * 64 + ((colb + ks2 * 16 + hi * 8) ^ sw2)]);
          o16[dt] = __builtin_amdgcn_mfma_f32_32x32x16_bf16(vf, pf, o16[dt], 0, 0, 0);
        }
        o_l = __builtin_amdgcn_mfma_f32_32x32x16_bf16(onesf, pf, o_l, 0, 0, 0);
        __builtin_amdgcn_s_setprio(0);
      }
    }
  }  // tt

  // final flush
  {
    const float lr = o_l[0];
    if (pcur >= 0) pwrite(Pp + (size_t)pcur * PSZ, lr);
    else epilogue(q0, lr, vbuf + (ntot & 1) * 8192);  // not read by last PV
  }
}

// Combine two kv-chunk partials per (bh, qt>=16): exact (common zero shift).
__global__ __launch_bounds__(128) void combine_kernel(const float* __restrict__ Pp,
                                                      ushort* __restrict__ Yg) {
  __shared__ ushort Yt[128 * 68];
  const int bid = blockIdx.x;        // 384
  const int bh = bid >> 4, qq = bid & 15;
  const int bb = bh / H, h = bh % H;
  const int q0 = (16 + qq) * 128;
  const int q = threadIdx.x;         // 0..127
  const float* P1 = Pp + (size_t)(bh * 16 + qq) * 2 * PSZ;
  const float* P2 = P1 + PSZ;
  const float inv = 1.0f / (P1[8192 + q] + P2[8192 + q]);
#pragma unroll 8
  for (int d = 0; d < 64; d++)
    Yt[q * 68 + d] = f2b((P1[d * 128 + q] + P2[d * 128 + q]) * inv);
  __syncthreads();
#pragma unroll
  for (int it = 0; it < 2; it++) {
    const int row = it * 64 + (q >> 1), half = q & 1;
#pragma unroll
    for (int seg = 0; seg < 4; seg++) {
      bf16x8 vv = *reinterpret_cast<const bf16x8*>(&Yt[row * 68 + half * 32 + seg * 8]);
      *reinterpret_cast<bf16x8*>(
          Yg + ((size_t)(bb * T + q0 + row)) * C + h * 64 + half * 32 + seg * 8) = vv;
    }
  }
}

extern "C" void kernel_launch(void* const* d_in, const int* in_sizes, int n_in,
                              void* d_out, int out_size, void* d_ws, size_t ws_size,
                              hipStream_t stream) {
  const float* x = (const float*)d_in[0];
  const float* Wa = (const float*)d_in[1];
  const float* ba = (const float*)d_in[2];
  const float* Wp = (const float*)d_in[3];
  const float* bp = (const float*)d_in[4];
  float* out = (float*)d_out;

  char* ws = (char*)d_ws;
  size_t off = 0;
  auto carve = [&](size_t bytes) {
    void* p = ws + off;
    off += (bytes + 255) & ~(size_t)255;
    return p;
  };
  ushort* xb   = (ushort*)carve((size_t)M * C * 2);
  ushort* WaT  = (ushort*)carve((size_t)N3 * C * 2);
  ushort* WpT  = (ushort*)carve((size_t)C * C * 2);
  ushort* Qb   = (ushort*)carve((size_t)BH * T * HD * 2);
  ushort* Kb   = (ushort*)carve((size_t)BH * T * HD * 2);
  ushort* Vtb  = (ushort*)carve((size_t)BH * HD * T * 2);
  ushort* Yb   = (ushort*)carve((size_t)M * C * 2);
  float*  Pp   = (float*)carve((size_t)BH * 16 * 2 * PSZ * 4);

  cvt_kernel<<<2048, 256, 0, stream>>>(x, xb, M * C);
  cvtT_kernel<<<dim3(C / 64, N3 / 64), 256, 0, stream>>>(Wa, WaT, C, N3);
  cvtT_kernel<<<dim3(C / 64, C / 64), 256, 0, stream>>>(Wp, WpT, C, C);

  gemm_kernel<0><<<dim3(N3 / 128, M / 128), 256, 0, stream>>>(
      xb, WaT, ba, N3, C, Qb, Kb, Vtb, nullptr);

  attn_kernel<<<dim3(768), 256, 0, stream>>>(Qb, Kb, Vtb, Yb, Pp);
  combine_kernel<<<dim3(BH * 16), 128, 0, stream>>>(Pp, Yb);

  gemm_kernel<1><<<dim3(C / 128, M / 128), 256, 0, stream>>>(
      Yb, WpT, bp, C, C, nullptr, nullptr, nullptr, out);
}

// Round 12
// 176.806 us; speedup vs baseline: 1.0689x; 1.0689x over previous
//
#include <hip/hip_runtime.h>
#include <hip/hip_bf16.h>

typedef __attribute__((ext_vector_type(8))) short bf16x8;
typedef __attribute__((ext_vector_type(4))) float f32x4;
typedef __attribute__((ext_vector_type(16))) float f32x16;
typedef __attribute__((ext_vector_type(4))) int i32x4;

#define DEVI __device__ __forceinline__

namespace {
constexpr int BATCH = 2;
constexpr int T = 4096;
constexpr int C = 768;
constexpr int H = 12;
constexpr int HD = 64;
constexpr int M = BATCH * T;     // 8192
constexpr int N3 = 3 * C;        // 2304
constexpr int BH = BATCH * H;    // 24
constexpr float QSCALE = 0.125f * 1.44269504088896f;  // 1/sqrt(64) * log2(e)
constexpr int PSZ = 64 * 128 + 128;  // partial: O^T f32 [64d][128q] + l[128]
}  // namespace

DEVI ushort f2b(float f) {
  union { float f; unsigned u; } v; v.f = f;
  unsigned r = (v.u + 0x7FFFu + ((v.u >> 16) & 1u)) >> 16;
  return (ushort)r;
}

DEVI f32x16 zero16() {
  f32x16 z;
#pragma unroll
  for (int i = 0; i < 16; i++) z[i] = 0.f;
  return z;
}

// async 16B global->LDS. LDS dest is wave-uniform base; HW adds lane*16.
DEVI void gload16(const void* g, void* l) {
  __builtin_amdgcn_global_load_lds(
      (const __attribute__((address_space(1))) unsigned int*)g,
      (__attribute__((address_space(3))) unsigned int*)l, 16, 0, 0);
}

__global__ __launch_bounds__(256) void cvt_kernel(const float* __restrict__ src,
                                                  ushort* __restrict__ dst, int n) {
  int i = (blockIdx.x * 256 + threadIdx.x) * 4;
  int stride = gridDim.x * 256 * 4;
  for (; i < n; i += stride) {
    float4 v = *reinterpret_cast<const float4*>(src + i);
    ushort4 o;
    o.x = f2b(v.x); o.y = f2b(v.y); o.z = f2b(v.z); o.w = f2b(v.w);
    *reinterpret_cast<ushort4*>(dst + i) = o;
  }
}

// Transpose-convert: f32 W [K][N] -> bf16 W^T [N][K]. 64x64 tiles.
__global__ __launch_bounds__(256) void cvtT_kernel(const float* __restrict__ src,
                                                   ushort* __restrict__ dst,
                                                   int K, int N) {
  __shared__ ushort Lt[64 * 68];
  const int k0 = blockIdx.x * 64, n0 = blockIdx.y * 64;
  const int tid = threadIdx.x;
  const int rr = tid >> 4, c4 = (tid & 15) * 4;
#pragma unroll
  for (int it = 0; it < 4; it++) {
    const int r = it * 16 + rr;
    float4 v = *reinterpret_cast<const float4*>(src + (size_t)(k0 + r) * N + n0 + c4);
    Lt[(c4 + 0) * 68 + r] = f2b(v.x);
    Lt[(c4 + 1) * 68 + r] = f2b(v.y);
    Lt[(c4 + 2) * 68 + r] = f2b(v.z);
    Lt[(c4 + 3) * 68 + r] = f2b(v.w);
  }
  __syncthreads();
#pragma unroll
  for (int it = 0; it < 4; it++) {
    const int r = it * 16 + rr;
    *reinterpret_cast<ushort4*>(dst + (size_t)(n0 + r) * K + k0 + c4) =
        *reinterpret_cast<const ushort4*>(&Lt[r * 68 + c4]);
  }
}

// m97-style GEMM: A [Mrows x Kd] bf16 row-major, Bt = B^T [N x Kd] bf16 row-major.
template <int EPI>
__global__ __launch_bounds__(256, 3) void gemm_kernel(
    const ushort* __restrict__ A, const ushort* __restrict__ Bt,
    const float* __restrict__ bias, int N, int Kd,
    ushort* __restrict__ qo, ushort* __restrict__ ko, ushort* __restrict__ vo,
    float* __restrict__ fo) {
  constexpr int BM = 128;
  constexpr int BN = 128;
  constexpr int WN = 2;                    // waves along n
  constexpr int WTN = BN / WN;             // 64
  constexpr int NT = WTN / 32;             // 2
  constexpr int CH_A = BM / 8;             // 1KB chunks in A tile
  constexpr int CH_B = BN / 8;
  constexpr int CPW = (CH_A + CH_B) / 4;
  constexpr int SMEM = (EPI == 0) ? (4 * 64 * 68) : ((BM + BN) * 64);
  __shared__ ushort smem[SMEM];
  ushort* As = smem;
  ushort* Bs = smem + BM * 64;

  const int tid = threadIdx.x;
  const int lane = tid & 63;
  const int w = tid >> 6;
  const int l31 = lane & 31;
  const int hi = lane >> 5;
  const int wm = w / WN, wn = w % WN;
  const int m0 = blockIdx.y * BM, n0 = blockIdx.x * BN;
  const int r8 = lane >> 3, c8 = lane & 7;
  const int csw = (c8 ^ r8) * 8;

  f32x16 acc[2][NT];
#pragma unroll
  for (int mt = 0; mt < 2; mt++)
#pragma unroll
    for (int nt = 0; nt < NT; nt++) acc[mt][nt] = zero16();

  for (int k0 = 0; k0 < Kd; k0 += 64) {
    __syncthreads();
#pragma unroll
    for (int ci = 0; ci < CPW; ci++) {
      const int chk = w * CPW + ci;
      if (chk < CH_A) {
        gload16(A + (size_t)(m0 + chk * 8 + r8) * Kd + k0 + csw, (char*)As + chk * 1024);
      } else {
        const int ch2 = chk - CH_A;
        gload16(Bt + (size_t)(n0 + ch2 * 8 + r8) * Kd + k0 + csw, (char*)Bs + ch2 * 1024);
      }
    }
    __syncthreads();
#pragma unroll
    for (int ks = 0; ks < 4; ks++) {
      bf16x8 af[2], bf[NT];
#pragma unroll
      for (int mt = 0; mt < 2; mt++) {
        const int rl = wm * 64 + mt * 32 + l31;
        af[mt] = *reinterpret_cast<const bf16x8*>(
            &As[rl * 64 + ((ks * 16 + hi * 8) ^ ((rl & 7) * 8))]);
      }
#pragma unroll
      for (int nt = 0; nt < NT; nt++) {
        const int nl = wn * WTN + nt * 32 + l31;
        bf[nt] = *reinterpret_cast<const bf16x8*>(
            &Bs[nl * 64 + ((ks * 16 + hi * 8) ^ ((nl & 7) * 8))]);
      }
#pragma unroll
      for (int mt = 0; mt < 2; mt++)
#pragma unroll
        for (int nt = 0; nt < NT; nt++)
          acc[mt][nt] = __builtin_amdgcn_mfma_f32_32x32x16_bf16(af[mt], bf[nt], acc[mt][nt], 0, 0, 0);
    }
  }

  // C layout (verified): col = l31, row = (r&3) + 8*(r>>2) + 4*hi
  if constexpr (EPI == 0) {
    if (n0 >= 1536) {
      __syncthreads();
      ushort* Vw = smem + w * 4352;  // [64 d][68]
      const float bv0 = bias[n0 + wn * 64 + l31];
      const float bv1 = bias[n0 + wn * 64 + 32 + l31];
#pragma unroll
      for (int mt = 0; mt < 2; mt++)
#pragma unroll
        for (int nt = 0; nt < 2; nt++) {
          const float bv = nt ? bv1 : bv0;
#pragma unroll
          for (int r = 0; r < 16; r++) {
            const int trow = mt * 32 + (r & 3) + ((r >> 2) << 3) + (hi << 2);
            Vw[(nt * 32 + l31) * 68 + trow] = f2b(acc[mt][nt][r] + bv);
          }
        }
      const int hh = (n0 - 1536) / 64 + wn;
      const int bb = m0 >> 12;
      const int t0 = (m0 & (T - 1)) + wm * 64;
      const size_t vbase = (size_t)((bb * H + hh) * 64 + lane) * T + t0;
#pragma unroll
      for (int x8 = 0; x8 < 8; x8++) {
        bf16x8 vv = *reinterpret_cast<const bf16x8*>(&Vw[lane * 68 + x8 * 8]);
        *reinterpret_cast<bf16x8*>(vo + vbase + ((x8 ^ (lane & 7)) * 8)) = vv;
      }
    } else {
#pragma unroll
      for (int mt = 0; mt < 2; mt++)
#pragma unroll
        for (int nt = 0; nt < 2; nt++) {
          const int n = n0 + wn * 64 + nt * 32 + l31;
          const float bv = bias[n];
          const int part = (n >= 768) ? 1 : 0;
          const int ci = n - part * 768;
          const int hh = ci >> 6, dd = ci & 63;
#pragma unroll
          for (int r = 0; r < 16; r++) {
            const int m = m0 + wm * 64 + mt * 32 + (r & 3) + ((r >> 2) << 3) + (hi << 2);
            const int bb = m >> 12, t = m & (T - 1);
            const float val = acc[mt][nt][r] + bv;
            if (part == 0) {
              qo[((size_t)(bb * H + hh) * T + t) * HD + dd] = f2b(val * QSCALE);
            } else {
              ko[((size_t)(bb * H + hh) * T + t) * HD + (dd ^ ((t & 7) << 3))] = f2b(val);
            }
          }
        }
    }
  } else {
#pragma unroll
    for (int mt = 0; mt < 2; mt++)
#pragma unroll
      for (int nt = 0; nt < NT; nt++) {
        const int n = n0 + wn * WTN + nt * 32 + l31;
        const float bv = bias[n];
#pragma unroll
        for (int r = 0; r < 16; r++) {
          const int m = m0 + wm * 64 + mt * 32 + (r & 3) + ((r >> 2) << 3) + (hi << 2);
          fo[(size_t)m * N + n] = acc[mt][nt][r] + bv;
        }
      }
  }
}

// Flash attention v12: round-10 structure (4 waves x 32q, KVBLK=128, K single-buf
// + V double-buf, 2 barriers/tile) + zero-shift softmax (p = exp2(s), VALU row
// sums) + ZF-seeded QK^T + per-block kv-tile rotation (order-independent sums).
__global__ __launch_bounds__(256, 3) void attn_kernel(
    const ushort* __restrict__ Qg, const ushort* __restrict__ Kg,
    const ushort* __restrict__ Vtg, ushort* __restrict__ Yg,
    float* __restrict__ Pp) {
  __shared__ ushort kbuf[128 * 64];         // 16KB: K [128kv][64k^swz]
  __shared__ ushort vbuf[2 * 2 * 64 * 64];  // 32KB: parity x kv64-subtile x [64d][64kv^swz]

  const int tid = threadIdx.x;
  const int lane = tid & 63;
  const int w = tid >> 6;            // 0..3
  const int l31 = lane & 31;
  const int hi = lane >> 5;
  const int r8 = lane >> 3, c8 = lane & 7;

  const int bid = blockIdx.x;
  const int xcd = bid & 7, idx = bid >> 3;   // 8 XCDs x 96
  const int bh = xcd * 3 + idx % 3;          // 3 heads per XCD (L2 locality)
  const int slot = idx / 3;                  // 0..31

  int qtA, qtB, kvbase, bnd, ntot, pA, pB;
  if (slot < 8) {
    qtA = slot; qtB = 15 - slot; kvbase = 0; bnd = slot + 1; ntot = 17; pA = -1; pB = -1;
  } else if (slot < 24) {
    qtA = slot + 8; qtB = -1; kvbase = 0; bnd = 100; ntot = 16;
    pA = (bh * 16 + (qtA - 16)) * 2; pB = -1;
  } else {
    const int a = slot - 24;
    qtA = 16 + a; qtB = 31 - a; kvbase = 16; bnd = a + 1; ntot = 17;
    pA = (bh * 16 + a) * 2 + 1; pB = (bh * 16 + (15 - a)) * 2 + 1;
  }

  // per-block rotation of each pass's tile order (zero-shift sums commute);
  // de-phases co-resident blocks so VALU/MFMA bursts interleave across blocks.
  const int lenA = (bnd < ntot) ? bnd : ntot;
  const int lenB = ntot - lenA;
  const int rotA = (lenA > 1) ? (bid % lenA) : 0;
  const int rotB = (lenB > 1) ? (bid % lenB) : 0;
  auto kvt_of = [&](int tt) {
    if (tt < lenA) {
      int i = tt + rotA; if (i >= lenA) i -= lenA;
      return kvbase + i;
    }
    int i = (tt - lenA) + rotB; if (i >= lenB) i -= lenB;
    return kvbase + i;
  };

  const int bb = bh / H, h = bh % H;
  const ushort* Qp = Qg + (size_t)bh * T * HD;
  const char* Kbp = (const char*)(Kg + (size_t)bh * T * HD);
  const char* Vbp = (const char*)(Vtg + (size_t)bh * HD * T);

  bf16x8 qcur[4];
#pragma unroll
  for (int ks = 0; ks < 4; ks++)
    qcur[ks] = *reinterpret_cast<const bf16x8*>(
        Qp + (size_t)(qtA * 128 + w * 32 + l31) * HD + ks * 16 + hi * 8);

  int q0 = qtA * 128, q0w = q0 + w * 32, qc = q0w + l31;
  int pcur = pA;

  const f32x16 ZF = zero16();  // persistent zero C-operand (never modified)

  f32x16 o16[2];
  o16[0] = zero16();
  o16[1] = zero16();
  float sa = 0.f, sb = 0.f, sc = 0.f, sd = 0.f;
  const int swz = (l31 & 7) << 3;

  auto issue_K = [&](int kvt) {
    const int kv0 = kvt * 128;
#pragma unroll
    for (int c2 = 0; c2 < 4; c2++) {
      const int chk = w * 4 + c2;  // 0..15, 8 kv-rows each
      gload16(Kbp + ((size_t)(kv0 + chk * 8 + r8) * 64 + c8 * 8) * 2,
              (char*)kbuf + chk * 1024);
    }
  };
  auto issue_V = [&](int kvt, int par) {
    const int kv0 = kvt * 128;
#pragma unroll
    for (int c2 = 0; c2 < 4; c2++) {
      const int chk = w * 4 + c2;       // 0..15
      const int st = chk >> 3;          // kv 64-block
      const int d8 = chk & 7;           // d-row group
      gload16(Vbp + ((size_t)(d8 * 8 + r8) * T + kv0 + st * 64 + c8 * 8) * 2,
              (char*)vbuf + par * 16384 + chk * 1024);
    }
  };

  auto epilogue = [&](int q0p, float lr, ushort* Ytb) {
    ushort* Yw = Ytb + w * 1152;  // per-wave [32 q][36]
    const float linv = 1.0f / lr;
#pragma unroll
    for (int dt = 0; dt < 2; dt++) {
#pragma unroll
      for (int r = 0; r < 16; r++) {
        const int d32 = (r & 3) + ((r >> 2) << 3) + (hi << 2);
        Yw[l31 * 36 + d32] = f2b(o16[dt][r] * linv);
      }
#pragma unroll
      for (int seg = 0; seg < 2; seg++) {
        bf16x8 vv = *reinterpret_cast<const bf16x8*>(&Yw[l31 * 36 + hi * 16 + seg * 8]);
        *reinterpret_cast<bf16x8*>(
            Yg + ((size_t)(bb * T + q0p + w * 32 + l31)) * C + h * 64 + dt * 32 +
            hi * 16 + seg * 8) = vv;
      }
    }
  };

  auto pwrite = [&](float* P, float lr) {
#pragma unroll
    for (int dt = 0; dt < 2; dt++)
#pragma unroll
      for (int r = 0; r < 16; r++) {
        const int d = dt * 32 + (r & 3) + ((r >> 2) << 3) + (hi << 2);
        P[d * 128 + w * 32 + l31] = o16[dt][r];
      }
    P[8192 + w * 32 + l31] = lr;
  };

  issue_K(kvt_of(0));
  issue_V(kvt_of(0), 0);

  for (int tt = 0; tt < ntot; tt++) {
    asm volatile("s_waitcnt vmcnt(0)" ::: "memory");  // K(tt) and V(tt) landed
    __builtin_amdgcn_s_barrier();
    __builtin_amdgcn_sched_barrier(0);

    if (tt == bnd) {  // flush pass A, switch to pass B
      float lr = (sa + sb) + (sc + sd);
      lr += __shfl_xor(lr, 32);
      if (pcur >= 0) pwrite(Pp + (size_t)pcur * PSZ, lr);
      else epilogue(q0, lr, vbuf + ((tt + 1) & 1) * 8192);  // dead V half
      o16[0] = zero16(); o16[1] = zero16();
      sa = sb = sc = sd = 0.f;
#pragma unroll
      for (int ks = 0; ks < 4; ks++)
        qcur[ks] = *reinterpret_cast<const bf16x8*>(
            Qp + (size_t)(qtB * 128 + w * 32 + l31) * HD + ks * 16 + hi * 8);
      q0 = qtB * 128; q0w = q0 + w * 32; qc = q0w + l31; pcur = pB;
    }

    const int kvt = kvt_of(tt);
    const int kv0 = kvt * 128;
    bool have[4], needm[4];
#pragma unroll
    for (int sub = 0; sub < 4; sub++) {
      have[sub] = (kv0 + sub * 32) <= (q0w + 31);
      needm[sub] = (kv0 + sub * 32 + 31) > q0w;  // false on full tiles
    }

    // S^T = K x Q^T, 4 kv-subs (first MFMA consumes persistent ZF)
    f32x16 s2[4];
#pragma unroll
    for (int sub = 0; sub < 4; sub++) {
      if (!have[sub]) continue;
      const int row = sub * 32 + l31;
      __builtin_amdgcn_s_setprio(1);
      bf16x8 kf = *reinterpret_cast<const bf16x8*>(&kbuf[row * 64 + ((hi * 8) ^ swz)]);
      f32x16 acc = __builtin_amdgcn_mfma_f32_32x32x16_bf16(kf, qcur[0], ZF, 0, 0, 0);
#pragma unroll
      for (int ks = 1; ks < 4; ks++) {
        kf = *reinterpret_cast<const bf16x8*>(
            &kbuf[row * 64 + ((ks * 16 + hi * 8) ^ swz)]);
        acc = __builtin_amdgcn_mfma_f32_32x32x16_bf16(kf, qcur[ks], acc, 0, 0, 0);
      }
      __builtin_amdgcn_s_setprio(0);
      if (needm[sub]) {
#pragma unroll
        for (int r2 = 0; r2 < 16; r2++) {
          const int kv = kv0 + sub * 32 + (r2 & 3) + ((r2 >> 2) << 3) + (hi << 2);
          if (kv > qc) acc[r2] = -1e30f;
        }
      }
      s2[sub] = acc;
    }

    asm volatile("s_waitcnt lgkmcnt(0)" ::: "memory");  // kbuf consumed
    __builtin_amdgcn_s_barrier();
    __builtin_amdgcn_sched_barrier(0);
    if (tt + 1 < ntot) {  // prefetch flies under softmax + PV
      const int nkvt = kvt_of(tt + 1);
      issue_K(nkvt);
      issue_V(nkvt, (tt + 1) & 1);
    }

    // zero-shift softmax: p = exp2(s); row-sums in 4 parallel VALU chains
#pragma unroll
    for (int sub = 0; sub < 4; sub++) {
      if (!have[sub]) continue;
#pragma unroll
      for (int r2 = 0; r2 < 16; r2 += 4) {
        s2[sub][r2]     = __builtin_amdgcn_exp2f(s2[sub][r2]);     sa += s2[sub][r2];
        s2[sub][r2 + 1] = __builtin_amdgcn_exp2f(s2[sub][r2 + 1]); sb += s2[sub][r2 + 1];
        s2[sub][r2 + 2] = __builtin_amdgcn_exp2f(s2[sub][r2 + 2]); sc += s2[sub][r2 + 2];
        s2[sub][r2 + 3] = __builtin_amdgcn_exp2f(s2[sub][r2 + 3]); sd += s2[sub][r2 + 3];
      }
    }

    // PV from vbuf[tt&1] (confirmed at loop top)
    const ushort* Vpar = vbuf + (tt & 1) * 8192;
#pragma unroll
    for (int sub = 0; sub < 4; sub++) {
      if (!have[sub]) continue;
      const ushort* Vst = Vpar + (sub >> 1) * 4096;
      const int colb = (sub & 1) * 32;
#pragma unroll
      for (int ks2 = 0; ks2 < 2; ks2++) {
        const int r0 = ks2 * 8;
        int a0, a1, b0, b1;
        asm("v_cvt_pk_bf16_f32 %0, %1, %2" : "=v"(a0) : "v"(s2[sub][r0 + 0]), "v"(s2[sub][r0 + 1]));
        asm("v_cvt_pk_bf16_f32 %0, %1, %2" : "=v"(a1) : "v"(s2[sub][r0 + 2]), "v"(s2[sub][r0 + 3]));
        asm("v_cvt_pk_bf16_f32 %0, %1, %2" : "=v"(b0) : "v"(s2[sub][r0 + 4]), "v"(s2[sub][r0 + 5]));
        asm("v_cvt_pk_bf16_f32 %0, %1, %2" : "=v"(b1) : "v"(s2[sub][r0 + 6]), "v"(s2[sub][r0 + 7]));
        asm("v_permlane32_swap_b32 %0, %1" : "+v"(a0), "+v"(b0));
        asm("v_permlane32_swap_b32 %0, %1" : "+v"(a1), "+v"(b1));
        const i32x4 pi = {a0, a1, b0, b1};
        const bf16x8 pf = __builtin_bit_cast(bf16x8, pi);
        __builtin_amdgcn_s_setprio(1);
#pragma unroll
        for (int dt = 0; dt < 2; dt++) {
          const int drow = dt * 32 + l31;
          const int sw2 = (drow & 7) << 3;
          bf16x8 vf = *reinterpret_cast<const bf16x8*>(
              &Vst[drow * 64 + ((colb + ks2 * 16 + hi * 8) ^ sw2)]);
          o16[dt] = __builtin_amdgcn_mfma_f32_32x32x16_bf16(vf, pf, o16[dt], 0, 0, 0);
        }
        __builtin_amdgcn_s_setprio(0);
      }
    }
  }  // tt

  // final flush
  {
    float lr = (sa + sb) + (sc + sd);
    lr += __shfl_xor(lr, 32);
    if (pcur >= 0) pwrite(Pp + (size_t)pcur * PSZ, lr);
    else epilogue(q0, lr, vbuf + (ntot & 1) * 8192);  // not read by last PV
  }
}

// Combine two kv-chunk partials per (bh, qt>=16): exact (common zero shift).
__global__ __launch_bounds__(128) void combine_kernel(const float* __restrict__ Pp,
                                                      ushort* __restrict__ Yg) {
  __shared__ ushort Yt[128 * 68];
  const int bid = blockIdx.x;        // 384
  const int bh = bid >> 4, qq = bid & 15;
  const int bb = bh / H, h = bh % H;
  const int q0 = (16 + qq) * 128;
  const int q = threadIdx.x;         // 0..127
  const float* P1 = Pp + (size_t)(bh * 16 + qq) * 2 * PSZ;
  const float* P2 = P1 + PSZ;
  const float inv = 1.0f / (P1[8192 + q] + P2[8192 + q]);
#pragma unroll 8
  for (int d = 0; d < 64; d++)
    Yt[q * 68 + d] = f2b((P1[d * 128 + q] + P2[d * 128 + q]) * inv);
  __syncthreads();
#pragma unroll
  for (int it = 0; it < 2; it++) {
    const int row = it * 64 + (q >> 1), half = q & 1;
#pragma unroll
    for (int seg = 0; seg < 4; seg++) {
      bf16x8 vv = *reinterpret_cast<const bf16x8*>(&Yt[row * 68 + half * 32 + seg * 8]);
      *reinterpret_cast<bf16x8*>(
          Yg + ((size_t)(bb * T + q0 + row)) * C + h * 64 + half * 32 + seg * 8) = vv;
    }
  }
}

extern "C" void kernel_launch(void* const* d_in, const int* in_sizes, int n_in,
                              void* d_out, int out_size, void* d_ws, size_t ws_size,
                              hipStream_t stream) {
  const float* x = (const float*)d_in[0];
  const float* Wa = (const float*)d_in[1];
  const float* ba = (const float*)d_in[2];
  const float* Wp = (const float*)d_in[3];
  const float* bp = (const float*)d_in[4];
  float* out = (float*)d_out;

  char* ws = (char*)d_ws;
  size_t off = 0;
  auto carve = [&](size_t bytes) {
    void* p = ws + off;
    off += (bytes + 255) & ~(size_t)255;
    return p;
  };
  ushort* xb   = (ushort*)carve((size_t)M * C * 2);
  ushort* WaT  = (ushort*)carve((size_t)N3 * C * 2);
  ushort* WpT  = (ushort*)carve((size_t)C * C * 2);
  ushort* Qb   = (ushort*)carve((size_t)BH * T * HD * 2);
  ushort* Kb   = (ushort*)carve((size_t)BH * T * HD * 2);
  ushort* Vtb  = (ushort*)carve((size_t)BH * HD * T * 2);
  ushort* Yb   = (ushort*)carve((size_t)M * C * 2);
  float*  Pp   = (float*)carve((size_t)BH * 16 * 2 * PSZ * 4);

  cvt_kernel<<<2048, 256, 0, stream>>>(x, xb, M * C);
  cvtT_kernel<<<dim3(C / 64, N3 / 64), 256, 0, stream>>>(Wa, WaT, C, N3);
  cvtT_kernel<<<dim3(C / 64, C / 64), 256, 0, stream>>>(Wp, WpT, C, C);

  gemm_kernel<0><<<dim3(N3 / 128, M / 128), 256, 0, stream>>>(
      xb, WaT, ba, N3, C, Qb, Kb, Vtb, nullptr);

  attn_kernel<<<dim3(768), 256, 0, stream>>>(Qb, Kb, Vtb, Yb, Pp);
  combine_kernel<<<dim3(BH * 16), 128, 0, stream>>>(Pp, Yb);

  gemm_kernel<1><<<dim3(C / 128, M / 128), 256, 0, stream>>>(
      Yb, WpT, bp, C, C, nullptr, nullptr, nullptr, out);
}

// Round 13
// 167.651 us; speedup vs baseline: 1.1273x; 1.0546x over previous
//
#include <hip/hip_runtime.h>
#include <hip/hip_bf16.h>

typedef __attribute__((ext_vector_type(8))) short bf16x8;
typedef __attribute__((ext_vector_type(4))) float f32x4;
typedef __attribute__((ext_vector_type(16))) float f32x16;
typedef __attribute__((ext_vector_type(4))) int i32x4;

#define DEVI __device__ __forceinline__

namespace {
constexpr int BATCH = 2;
constexpr int T = 4096;
constexpr int C = 768;
constexpr int H = 12;
constexpr int HD = 64;
constexpr int M = BATCH * T;     // 8192
constexpr int N3 = 3 * C;        // 2304
constexpr int BH = BATCH * H;    // 24
constexpr float QSCALE = 0.125f * 1.44269504088896f;  // 1/sqrt(64) * log2(e)
constexpr int PSZ = 64 * 128 + 128;  // partial: O^T f32 [64d][128q] + l[128]
}  // namespace

DEVI ushort f2b(float f) {
  union { float f; unsigned u; } v; v.f = f;
  unsigned r = (v.u + 0x7FFFu + ((v.u >> 16) & 1u)) >> 16;
  return (ushort)r;
}

DEVI f32x16 zero16() {
  f32x16 z;
#pragma unroll
  for (int i = 0; i < 16; i++) z[i] = 0.f;
  return z;
}

// async 16B global->LDS. LDS dest is wave-uniform base; HW adds lane*16.
DEVI void gload16(const void* g, void* l) {
  __builtin_amdgcn_global_load_lds(
      (const __attribute__((address_space(1))) unsigned int*)g,
      (__attribute__((address_space(3))) unsigned int*)l, 16, 0, 0);
}

__global__ __launch_bounds__(256) void cvt_kernel(const float* __restrict__ src,
                                                  ushort* __restrict__ dst, int n) {
  int i = (blockIdx.x * 256 + threadIdx.x) * 4;
  int stride = gridDim.x * 256 * 4;
  for (; i < n; i += stride) {
    float4 v = *reinterpret_cast<const float4*>(src + i);
    ushort4 o;
    o.x = f2b(v.x); o.y = f2b(v.y); o.z = f2b(v.z); o.w = f2b(v.w);
    *reinterpret_cast<ushort4*>(dst + i) = o;
  }
}

// Transpose-convert: f32 W [K][N] -> bf16 W^T [N][K]. 64x64 tiles.
__global__ __launch_bounds__(256) void cvtT_kernel(const float* __restrict__ src,
                                                   ushort* __restrict__ dst,
                                                   int K, int N) {
  __shared__ ushort Lt[64 * 68];
  const int k0 = blockIdx.x * 64, n0 = blockIdx.y * 64;
  const int tid = threadIdx.x;
  const int rr = tid >> 4, c4 = (tid & 15) * 4;
#pragma unroll
  for (int it = 0; it < 4; it++) {
    const int r = it * 16 + rr;
    float4 v = *reinterpret_cast<const float4*>(src + (size_t)(k0 + r) * N + n0 + c4);
    Lt[(c4 + 0) * 68 + r] = f2b(v.x);
    Lt[(c4 + 1) * 68 + r] = f2b(v.y);
    Lt[(c4 + 2) * 68 + r] = f2b(v.z);
    Lt[(c4 + 3) * 68 + r] = f2b(v.w);
  }
  __syncthreads();
#pragma unroll
  for (int it = 0; it < 4; it++) {
    const int r = it * 16 + rr;
    *reinterpret_cast<ushort4*>(dst + (size_t)(n0 + r) * K + k0 + c4) =
        *reinterpret_cast<const ushort4*>(&Lt[r * 68 + c4]);
  }
}

// m97-style GEMM: A [Mrows x Kd] bf16 row-major, Bt = B^T [N x Kd] bf16 row-major.
template <int EPI>
__global__ __launch_bounds__(256, 3) void gemm_kernel(
    const ushort* __restrict__ A, const ushort* __restrict__ Bt,
    const float* __restrict__ bias, int N, int Kd,
    ushort* __restrict__ qo, ushort* __restrict__ ko, ushort* __restrict__ vo,
    float* __restrict__ fo) {
  constexpr int BM = 128;
  constexpr int BN = 128;
  constexpr int WN = 2;                    // waves along n
  constexpr int WTN = BN / WN;             // 64
  constexpr int NT = WTN / 32;             // 2
  constexpr int CH_A = BM / 8;             // 1KB chunks in A tile
  constexpr int CH_B = BN / 8;
  constexpr int CPW = (CH_A + CH_B) / 4;
  constexpr int SMEM = (EPI == 0) ? (4 * 64 * 68) : ((BM + BN) * 64);
  __shared__ ushort smem[SMEM];
  ushort* As = smem;
  ushort* Bs = smem + BM * 64;

  const int tid = threadIdx.x;
  const int lane = tid & 63;
  const int w = tid >> 6;
  const int l31 = lane & 31;
  const int hi = lane >> 5;
  const int wm = w / WN, wn = w % WN;
  const int m0 = blockIdx.y * BM, n0 = blockIdx.x * BN;
  const int r8 = lane >> 3, c8 = lane & 7;
  const int csw = (c8 ^ r8) * 8;

  f32x16 acc[2][NT];
#pragma unroll
  for (int mt = 0; mt < 2; mt++)
#pragma unroll
    for (int nt = 0; nt < NT; nt++) acc[mt][nt] = zero16();

  for (int k0 = 0; k0 < Kd; k0 += 64) {
    __syncthreads();
#pragma unroll
    for (int ci = 0; ci < CPW; ci++) {
      const int chk = w * CPW + ci;
      if (chk < CH_A) {
        gload16(A + (size_t)(m0 + chk * 8 + r8) * Kd + k0 + csw, (char*)As + chk * 1024);
      } else {
        const int ch2 = chk - CH_A;
        gload16(Bt + (size_t)(n0 + ch2 * 8 + r8) * Kd + k0 + csw, (char*)Bs + ch2 * 1024);
      }
    }
    __syncthreads();
#pragma unroll
    for (int ks = 0; ks < 4; ks++) {
      bf16x8 af[2], bf[NT];
#pragma unroll
      for (int mt = 0; mt < 2; mt++) {
        const int rl = wm * 64 + mt * 32 + l31;
        af[mt] = *reinterpret_cast<const bf16x8*>(
            &As[rl * 64 + ((ks * 16 + hi * 8) ^ ((rl & 7) * 8))]);
      }
#pragma unroll
      for (int nt = 0; nt < NT; nt++) {
        const int nl = wn * WTN + nt * 32 + l31;
        bf[nt] = *reinterpret_cast<const bf16x8*>(
            &Bs[nl * 64 + ((ks * 16 + hi * 8) ^ ((nl & 7) * 8))]);
      }
#pragma unroll
      for (int mt = 0; mt < 2; mt++)
#pragma unroll
        for (int nt = 0; nt < NT; nt++)
          acc[mt][nt] = __builtin_amdgcn_mfma_f32_32x32x16_bf16(af[mt], bf[nt], acc[mt][nt], 0, 0, 0);
    }
  }

  // C layout (verified): col = l31, row = (r&3) + 8*(r>>2) + 4*hi
  if constexpr (EPI == 0) {
    if (n0 >= 1536) {
      __syncthreads();
      ushort* Vw = smem + w * 4352;  // [64 d][68]
      const float bv0 = bias[n0 + wn * 64 + l31];
      const float bv1 = bias[n0 + wn * 64 + 32 + l31];
#pragma unroll
      for (int mt = 0; mt < 2; mt++)
#pragma unroll
        for (int nt = 0; nt < 2; nt++) {
          const float bv = nt ? bv1 : bv0;
#pragma unroll
          for (int r = 0; r < 16; r++) {
            const int trow = mt * 32 + (r & 3) + ((r >> 2) << 3) + (hi << 2);
            Vw[(nt * 32 + l31) * 68 + trow] = f2b(acc[mt][nt][r] + bv);
          }
        }
      const int hh = (n0 - 1536) / 64 + wn;
      const int bb = m0 >> 12;
      const int t0 = (m0 & (T - 1)) + wm * 64;
      const size_t vbase = (size_t)((bb * H + hh) * 64 + lane) * T + t0;
#pragma unroll
      for (int x8 = 0; x8 < 8; x8++) {
        bf16x8 vv = *reinterpret_cast<const bf16x8*>(&Vw[lane * 68 + x8 * 8]);
        *reinterpret_cast<bf16x8*>(vo + vbase + ((x8 ^ (lane & 7)) * 8)) = vv;
      }
    } else {
#pragma unroll
      for (int mt = 0; mt < 2; mt++)
#pragma unroll
        for (int nt = 0; nt < 2; nt++) {
          const int n = n0 + wn * 64 + nt * 32 + l31;
          const float bv = bias[n];
          const int part = (n >= 768) ? 1 : 0;
          const int ci = n - part * 768;
          const int hh = ci >> 6, dd = ci & 63;
#pragma unroll
          for (int r = 0; r < 16; r++) {
            const int m = m0 + wm * 64 + mt * 32 + (r & 3) + ((r >> 2) << 3) + (hi << 2);
            const int bb = m >> 12, t = m & (T - 1);
            const float val = acc[mt][nt][r] + bv;
            if (part == 0) {
              qo[((size_t)(bb * H + hh) * T + t) * HD + dd] = f2b(val * QSCALE);
            } else {
              ko[((size_t)(bb * H + hh) * T + t) * HD + (dd ^ ((t & 7) << 3))] = f2b(val);
            }
          }
        }
    }
  } else {
#pragma unroll
    for (int mt = 0; mt < 2; mt++)
#pragma unroll
      for (int nt = 0; nt < NT; nt++) {
        const int n = n0 + wn * WTN + nt * 32 + l31;
        const float bv = bias[n];
#pragma unroll
        for (int r = 0; r < 16; r++) {
          const int m = m0 + wm * 64 + mt * 32 + (r & 3) + ((r >> 2) << 3) + (hi << 2);
          fo[(size_t)m * N + n] = acc[mt][nt][r] + bv;
        }
      }
  }
}

// Flash attention v13: round-10 structure (4 waves x 32q, KVBLK=128, K single-buf
// + V double-buf, 2 barriers/tile, sequential kv order) + zero-shift softmax
// (p = exp2(s), VALU row sums) + ZF-seeded QK^T. No tile rotation (L2 locality).
__global__ __launch_bounds__(256, 3) void attn_kernel(
    const ushort* __restrict__ Qg, const ushort* __restrict__ Kg,
    const ushort* __restrict__ Vtg, ushort* __restrict__ Yg,
    float* __restrict__ Pp) {
  __shared__ ushort kbuf[128 * 64];         // 16KB: K [128kv][64k^swz]
  __shared__ ushort vbuf[2 * 2 * 64 * 64];  // 32KB: parity x kv64-subtile x [64d][64kv^swz]

  const int tid = threadIdx.x;
  const int lane = tid & 63;
  const int w = tid >> 6;            // 0..3
  const int l31 = lane & 31;
  const int hi = lane >> 5;
  const int r8 = lane >> 3, c8 = lane & 7;

  const int bid = blockIdx.x;
  const int xcd = bid & 7, idx = bid >> 3;   // 8 XCDs x 96
  const int bh = xcd * 3 + idx % 3;          // 3 heads per XCD (L2 locality)
  const int slot = idx / 3;                  // 0..31

  int qtA, qtB, kvbase, bnd, ntot, pA, pB;
  if (slot < 8) {
    qtA = slot; qtB = 15 - slot; kvbase = 0; bnd = slot + 1; ntot = 17; pA = -1; pB = -1;
  } else if (slot < 24) {
    qtA = slot + 8; qtB = -1; kvbase = 0; bnd = 100; ntot = 16;
    pA = (bh * 16 + (qtA - 16)) * 2; pB = -1;
  } else {
    const int a = slot - 24;
    qtA = 16 + a; qtB = 31 - a; kvbase = 16; bnd = a + 1; ntot = 17;
    pA = (bh * 16 + a) * 2 + 1; pB = (bh * 16 + (15 - a)) * 2 + 1;
  }

  const int bb = bh / H, h = bh % H;
  const ushort* Qp = Qg + (size_t)bh * T * HD;
  const char* Kbp = (const char*)(Kg + (size_t)bh * T * HD);
  const char* Vbp = (const char*)(Vtg + (size_t)bh * HD * T);

  bf16x8 qcur[4];
#pragma unroll
  for (int ks = 0; ks < 4; ks++)
    qcur[ks] = *reinterpret_cast<const bf16x8*>(
        Qp + (size_t)(qtA * 128 + w * 32 + l31) * HD + ks * 16 + hi * 8);

  int q0 = qtA * 128, q0w = q0 + w * 32, qc = q0w + l31;
  int pcur = pA;

  const f32x16 ZF = zero16();  // persistent zero C-operand (never modified)

  f32x16 o16[2];
  o16[0] = zero16();
  o16[1] = zero16();
  float sa = 0.f, sb = 0.f, sc = 0.f, sd = 0.f;
  const int swz = (l31 & 7) << 3;

  auto kvt_of = [&](int tt) { return kvbase + (tt < bnd ? tt : tt - bnd); };

  auto issue_K = [&](int kvt) {
    const int kv0 = kvt * 128;
#pragma unroll
    for (int c2 = 0; c2 < 4; c2++) {
      const int chk = w * 4 + c2;  // 0..15, 8 kv-rows each
      gload16(Kbp + ((size_t)(kv0 + chk * 8 + r8) * 64 + c8 * 8) * 2,
              (char*)kbuf + chk * 1024);
    }
  };
  auto issue_V = [&](int kvt, int par) {
    const int kv0 = kvt * 128;
#pragma unroll
    for (int c2 = 0; c2 < 4; c2++) {
      const int chk = w * 4 + c2;       // 0..15
      const int st = chk >> 3;          // kv 64-block
      const int d8 = chk & 7;           // d-row group
      gload16(Vbp + ((size_t)(d8 * 8 + r8) * T + kv0 + st * 64 + c8 * 8) * 2,
              (char*)vbuf + par * 16384 + chk * 1024);
    }
  };

  auto epilogue = [&](int q0p, float lr, ushort* Ytb) {
    ushort* Yw = Ytb + w * 1152;  // per-wave [32 q][36]
    const float linv = 1.0f / lr;
#pragma unroll
    for (int dt = 0; dt < 2; dt++) {
#pragma unroll
      for (int r = 0; r < 16; r++) {
        const int d32 = (r & 3) + ((r >> 2) << 3) + (hi << 2);
        Yw[l31 * 36 + d32] = f2b(o16[dt][r] * linv);
      }
#pragma unroll
      for (int seg = 0; seg < 2; seg++) {
        bf16x8 vv = *reinterpret_cast<const bf16x8*>(&Yw[l31 * 36 + hi * 16 + seg * 8]);
        *reinterpret_cast<bf16x8*>(
            Yg + ((size_t)(bb * T + q0p + w * 32 + l31)) * C + h * 64 + dt * 32 +
            hi * 16 + seg * 8) = vv;
      }
    }
  };

  auto pwrite = [&](float* P, float lr) {
#pragma unroll
    for (int dt = 0; dt < 2; dt++)
#pragma unroll
      for (int r = 0; r < 16; r++) {
        const int d = dt * 32 + (r & 3) + ((r >> 2) << 3) + (hi << 2);
        P[d * 128 + w * 32 + l31] = o16[dt][r];
      }
    P[8192 + w * 32 + l31] = lr;
  };

  issue_K(kvt_of(0));
  issue_V(kvt_of(0), 0);

  for (int tt = 0; tt < ntot; tt++) {
    asm volatile("s_waitcnt vmcnt(0)" ::: "memory");  // K(tt) and V(tt) landed
    __builtin_amdgcn_s_barrier();
    __builtin_amdgcn_sched_barrier(0);

    if (tt == bnd) {  // flush pass A, switch to pass B
      float lr = (sa + sb) + (sc + sd);
      lr += __shfl_xor(lr, 32);
      if (pcur >= 0) pwrite(Pp + (size_t)pcur * PSZ, lr);
      else epilogue(q0, lr, vbuf + ((tt + 1) & 1) * 8192);  // dead V half
      o16[0] = zero16(); o16[1] = zero16();
      sa = sb = sc = sd = 0.f;
#pragma unroll
      for (int ks = 0; ks < 4; ks++)
        qcur[ks] = *reinterpret_cast<const bf16x8*>(
            Qp + (size_t)(qtB * 128 + w * 32 + l31) * HD + ks * 16 + hi * 8);
      q0 = qtB * 128; q0w = q0 + w * 32; qc = q0w + l31; pcur = pB;
    }

    const int kvt = kvt_of(tt);
    const int kv0 = kvt * 128;
    bool have[4], needm[4];
#pragma unroll
    for (int sub = 0; sub < 4; sub++) {
      have[sub] = (kv0 + sub * 32) <= (q0w + 31);
      needm[sub] = (kv0 + sub * 32 + 31) > q0w;  // false on full tiles
    }

    // S^T = K x Q^T, 4 kv-subs (first MFMA consumes persistent ZF)
    f32x16 s2[4];
#pragma unroll
    for (int sub = 0; sub < 4; sub++) {
      if (!have[sub]) continue;
      const int row = sub * 32 + l31;
      __builtin_amdgcn_s_setprio(1);
      bf16x8 kf = *reinterpret_cast<const bf16x8*>(&kbuf[row * 64 + ((hi * 8) ^ swz)]);
      f32x16 acc = __builtin_amdgcn_mfma_f32_32x32x16_bf16(kf, qcur[0], ZF, 0, 0, 0);
#pragma unroll
      for (int ks = 1; ks < 4; ks++) {
        kf = *reinterpret_cast<const bf16x8*>(
            &kbuf[row * 64 + ((ks * 16 + hi * 8) ^ swz)]);
        acc = __builtin_amdgcn_mfma_f32_32x32x16_bf16(kf, qcur[ks], acc, 0, 0, 0);
      }
      __builtin_amdgcn_s_setprio(0);
      if (needm[sub]) {
#pragma unroll
        for (int r2 = 0; r2 < 16; r2++) {
          const int kv = kv0 + sub * 32 + (r2 & 3) + ((r2 >> 2) << 3) + (hi << 2);
          if (kv > qc) acc[r2] = -1e30f;
        }
      }
      s2[sub] = acc;
    }

    asm volatile("s_waitcnt lgkmcnt(0)" ::: "memory");  // kbuf consumed
    __builtin_amdgcn_s_barrier();
    __builtin_amdgcn_sched_barrier(0);
    if (tt + 1 < ntot) {  // prefetch flies under softmax + PV
      const int nkvt = kvt_of(tt + 1);
      issue_K(nkvt);
      issue_V(nkvt, (tt + 1) & 1);
    }

    // zero-shift softmax: p = exp2(s); row-sums in 4 parallel VALU chains
#pragma unroll
    for (int sub = 0; sub < 4; sub++) {
      if (!have[sub]) continue;
#pragma unroll
      for (int r2 = 0; r2 < 16; r2 += 4) {
        s2[sub][r2]     = __builtin_amdgcn_exp2f(s2[sub][r2]);     sa += s2[sub][r2];
        s2[sub][r2 + 1] = __builtin_amdgcn_exp2f(s2[sub][r2 + 1]); sb += s2[sub][r2 + 1];
        s2[sub][r2 + 2] = __builtin_amdgcn_exp2f(s2[sub][r2 + 2]); sc += s2[sub][r2 + 2];
        s2[sub][r2 + 3] = __builtin_amdgcn_exp2f(s2[sub][r2 + 3]); sd += s2[sub][r2 + 3];
      }
    }

    // PV from vbuf[tt&1] (confirmed at loop top)
    const ushort* Vpar = vbuf + (tt & 1) * 8192;
#pragma unroll
    for (int sub = 0; sub < 4; sub++) {
      if (!have[sub]) continue;
      const ushort* Vst = Vpar + (sub >> 1) * 4096;
      const int colb = (sub & 1) * 32;
#pragma unroll
      for (int ks2 = 0; ks2 < 2; ks2++) {
        const int r0 = ks2 * 8;
        int a0, a1, b0, b1;
        asm("v_cvt_pk_bf16_f32 %0, %1, %2" : "=v"(a0) : "v"(s2[sub][r0 + 0]), "v"(s2[sub][r0 + 1]));
        asm("v_cvt_pk_bf16_f32 %0, %1, %2" : "=v"(a1) : "v"(s2[sub][r0 + 2]), "v"(s2[sub][r0 + 3]));
        asm("v_cvt_pk_bf16_f32 %0, %1, %2" : "=v"(b0) : "v"(s2[sub][r0 + 4]), "v"(s2[sub][r0 + 5]));
        asm("v_cvt_pk_bf16_f32 %0, %1, %2" : "=v"(b1) : "v"(s2[sub][r0 + 6]), "v"(s2[sub][r0 + 7]));
        asm("v_permlane32_swap_b32 %0, %1" : "+v"(a0), "+v"(b0));
        asm("v_permlane32_swap_b32 %0, %1" : "+v"(a1), "+v"(b1));
        const i32x4 pi = {a0, a1, b0, b1};
        const bf16x8 pf = __builtin_bit_cast(bf16x8, pi);
        __builtin_amdgcn_s_setprio(1);
#pragma unroll
        for (int dt = 0; dt < 2; dt++) {
          const int drow = dt * 32 + l31;
          const int sw2 = (drow & 7) << 3;
          bf16x8 vf = *reinterpret_cast<const bf16x8*>(
              &Vst[drow * 64 + ((colb + ks2 * 16 + hi * 8) ^ sw2)]);
          o16[dt] = __builtin_amdgcn_mfma_f32_32x32x16_bf16(vf, pf, o16[dt], 0, 0, 0);
        }
        __builtin_amdgcn_s_setprio(0);
      }
    }
  }  // tt

  // final flush
  {
    float lr = (sa + sb) + (sc + sd);
    lr += __shfl_xor(lr, 32);
    if (pcur >= 0) pwrite(Pp + (size_t)pcur * PSZ, lr);
    else epilogue(q0, lr, vbuf + (ntot & 1) * 8192);  // not read by last PV
  }
}

// Combine two kv-chunk partials per (bh, qt>=16): exact (common zero shift).
__global__ __launch_bounds__(128) void combine_kernel(const float* __restrict__ Pp,
                                                      ushort* __restrict__ Yg) {
  __shared__ ushort Yt[128 * 68];
  const int bid = blockIdx.x;        // 384
  const int bh = bid >> 4, qq = bid & 15;
  const int bb = bh / H, h = bh % H;
  const int q0 = (16 + qq) * 128;
  const int q = threadIdx.x;         // 0..127
  const float* P1 = Pp + (size_t)(bh * 16 + qq) * 2 * PSZ;
  const float* P2 = P1 + PSZ;
  const float inv = 1.0f / (P1[8192 + q] + P2[8192 + q]);
#pragma unroll 8
  for (int d = 0; d < 64; d++)
    Yt[q * 68 + d] = f2b((P1[d * 128 + q] + P2[d * 128 + q]) * inv);
  __syncthreads();
#pragma unroll
  for (int it = 0; it < 2; it++) {
    const int row = it * 64 + (q >> 1), half = q & 1;
#pragma unroll
    for (int seg = 0; seg < 4; seg++) {
      bf16x8 vv = *reinterpret_cast<const bf16x8*>(&Yt[row * 68 + half * 32 + seg * 8]);
      *reinterpret_cast<bf16x8*>(
          Yg + ((size_t)(bb * T + q0 + row)) * C + h * 64 + half * 32 + seg * 8) = vv;
    }
  }
}

extern "C" void kernel_launch(void* const* d_in, const int* in_sizes, int n_in,
                              void* d_out, int out_size, void* d_ws, size_t ws_size,
                              hipStream_t stream) {
  const float* x = (const float*)d_in[0];
  const float* Wa = (const float*)d_in[1];
  const float* ba = (const float*)d_in[2];
  const float* Wp = (const float*)d_in[3];
  const float* bp = (const float*)d_in[4];
  float* out = (float*)d_out;

  char* ws = (char*)d_ws;
  size_t off = 0;
  auto carve = [&](size_t bytes) {
    void* p = ws + off;
    off += (bytes + 255) & ~(size_t)255;
    return p;
  };
  ushort* xb   = (ushort*)carve((size_t)M * C * 2);
  ushort* WaT  = (ushort*)carve((size_t)N3 * C * 2);
  ushort* WpT  = (ushort*)carve((size_t)C * C * 2);
  ushort* Qb   = (ushort*)carve((size_t)BH * T * HD * 2);
  ushort* Kb   = (ushort*)carve((size_t)BH * T * HD * 2);
  ushort* Vtb  = (ushort*)carve((size_t)BH * HD * T * 2);
  ushort* Yb   = (ushort*)carve((size_t)M * C * 2);
  float*  Pp   = (float*)carve((size_t)BH * 16 * 2 * PSZ * 4);

  cvt_kernel<<<2048, 256, 0, stream>>>(x, xb, M * C);
  cvtT_kernel<<<dim3(C / 64, N3 / 64), 256, 0, stream>>>(Wa, WaT, C, N3);
  cvtT_kernel<<<dim3(C / 64, C / 64), 256, 0, stream>>>(Wp, WpT, C, C);

  gemm_kernel<0><<<dim3(N3 / 128, M / 128), 256, 0, stream>>>(
      xb, WaT, ba, N3, C, Qb, Kb, Vtb, nullptr);

  attn_kernel<<<dim3(768), 256, 0, stream>>>(Qb, Kb, Vtb, Yb, Pp);
  combine_kernel<<<dim3(BH * 16), 128, 0, stream>>>(Pp, Yb);

  gemm_kernel<1><<<dim3(C / 128, M / 128), 256, 0, stream>>>(
      Yb, WpT, bp, C, C, nullptr, nullptr, nullptr, out);
}